// Round 1
// baseline (309.844 us; speedup 1.0000x reference)
//
#include <hip/hip_runtime.h>
#include <hip/hip_cooperative_groups.h>
#include <cstdint>
#include <cstddef>

namespace cg = cooperative_groups;

#define N_ANCH 25200
#define NB0 19200
#define NB1 24000
#define TOPK_N 4096
#define CONF_T 0.001
#define NMS_T 0.6
#define IMGS 640.0
#define NBINS 8192       // fp32 bits >> 17 (exponent + 6 mantissa bits), scores in (0,2)
#define JS 32            // j-split for rank phase
#define NBLK 256         // one block per CU (cooperative residency guaranteed)
#define NTHR 512

typedef unsigned long long u64;

struct WS {
  alignas(64) double sc[N_ANCH];       // masked score (sc or -1.0)
  alignas(64) double box[N_ANCH][4];   // clipped normalized boxes, fp64
  alignas(64) int    cls[N_ANCH];
  alignas(64) int    binv[N_ANCH];     // score bin per anchor
  alignas(64) int    rank[N_ANCH];     // rank within subset (by subset position)
  alignas(64) int    subset[N_ANCH];   // anchor ids with bin >= t_bin
  alignas(64) double ssc[N_ANCH];      // packed scores of subset
  alignas(64) int    hist[NBINS];      // global score-bin histogram (phase-0 zeroed)
  alignas(64) u64    hasSup[64];       // bit i of word (i>>6): row i has >=1 suppressor
  int    m_count;
  int    t_bin;
  alignas(64) double tbox[TOPK_N][4];
  alignas(64) double tarea[TOPK_N];
  alignas(64) double tsc[TOPK_N];
  alignas(64) int    tcls[TOPK_N];
  alignas(64) u64    supT[TOPK_N * 64]; // supT[i*64+w] bit b: j=w*64+b suppresses i
};

__device__ __forceinline__ double dsigmoid(double x) { return 1.0 / (1.0 + exp(-x)); }

__device__ __forceinline__ int score_bin(double sc) {
  if (sc < 0.0) return 0;                          // masked
  return (int)(__float_as_uint((float)sc) >> 17);  // monotone for positive floats, < 8192
}

// One cooperative kernel: 8 phases separated by grid.sync().
// NO early returns anywhere before the last grid.sync — every thread hits every sync.
__global__ void __launch_bounds__(NTHR)
k_all(const float* __restrict__ ps, const float* __restrict__ pm,
      const float* __restrict__ pl, const float* __restrict__ anch,
      WS* __restrict__ ws, float* __restrict__ out) {
  cg::grid_group grid = cg::this_grid();
  const int tid  = threadIdx.x;
  const int bid  = blockIdx.x;
  const int gtid = bid * NTHR + tid;

  // shared memory (all phases, top-level so there is no scoped-overlay surprise)
  __shared__ int    part[NTHR];        // select scan
  __shared__ double sjD[NTHR];         // rank j-stage
  __shared__ int    ajA[NTHR];
  __shared__ double jbD[128][5];       // iou j-stage (2 words = 128 j per tile)
  __shared__ int    jcA[128];
  __shared__ u64    hsArr[64];         // nms
  __shared__ int    lst[TOPK_N];

  // ---------------- phase 0: zero hist / hasSup / m_count ----------------
  if (gtid < NBINS) ws->hist[gtid] = 0;
  else if (gtid < NBINS + 64) ws->hasSup[gtid - NBINS] = 0ull;
  else if (gtid == NBINS + 64) ws->m_count = 0;
  grid.sync();

  // ---------------- phase 1: decode (4 lanes per anchor) + hist atomics --
  {
    int a = gtid >> 2;
    int r = gtid & 3;
    if (a < N_ANCH) {
      const float* p; int W, base, lvl; double stride;
      if (a < NB0)      { p = ps; W = 80; base = 0;   lvl = 0; stride = 8.0; }
      else if (a < NB1) { p = pm; W = 40; base = NB0; lvl = 1; stride = 16.0; }
      else              { p = pl; W = 20; base = NB1; lvl = 2; stride = 32.0; }
      int e = a - base;
      int pos = e / 3;
      int k = e - 3 * pos;
      int HW = W * W;

      // class max/argmax + softmax denom, 20 classes per lane
      const float* pc = p + (size_t)(3 + k * 80) * HW + pos;
      double m = -1e300, ssum = 0.0; int am = 0;
      for (int t = 0; t < 20; ++t) {
        int c = r + 4 * t;
        double v = (double)pc[(size_t)c * HW];
        ssum += exp(v);
        if (v > m) { m = v; am = c; }   // strict > keeps first occurrence per lane
      }
      // team reduction (teams of 4 are wave-aligned)
      for (int off = 1; off <= 2; off <<= 1) {
        double om = __shfl_xor(m, off);
        int oam   = __shfl_xor(am, off);
        double os = __shfl_xor(ssum, off);
        ssum += os;
        if (om > m || (om == m && oam < am)) { m = om; am = oam; }
      }

      if (r == 0) {
        double sobj = dsigmoid((double)p[(size_t)k * HW + pos]);
        double sc = sobj * (exp(m) / ssum);

        int x = pos % W, y = pos / W;
        const float* pr = p + (size_t)(243 + k * 4) * HW + pos;
        double tx = (double)pr[0];
        double ty = (double)pr[(size_t)HW];
        double tw = (double)pr[(size_t)2 * HW];
        double th = (double)pr[(size_t)3 * HW];
        double cx = (dsigmoid(tx) + (double)x) * stride;
        double cy = (dsigmoid(ty) + (double)y) * stride;
        double aw = (double)anch[lvl * 6 + k * 2 + 0];
        double ah = (double)anch[lvl * 6 + k * 2 + 1];
        double bw = exp(tw) * aw;
        double bh = exp(th) * ah;
        double x1 = fmin(fmax((cx - 0.5 * bw) / IMGS, 0.0), 1.0);
        double y1 = fmin(fmax((cy - 0.5 * bh) / IMGS, 0.0), 1.0);
        double x2 = fmin(fmax((cx + 0.5 * bw) / IMGS, 0.0), 1.0);
        double y2 = fmin(fmax((cy + 0.5 * bh) / IMGS, 0.0), 1.0);

        ws->box[a][0] = x1; ws->box[a][1] = y1;
        ws->box[a][2] = x2; ws->box[a][3] = y2;
        ws->cls[a] = am;
        double scm = (sc >= CONF_T) ? sc : -1.0;
        ws->sc[a] = scm;
        int bv = score_bin(scm);
        ws->binv[a] = bv;
        atomicAdd(&ws->hist[bv], 1);
      }
    }
  }
  grid.sync();

  // ---------------- phase 2: t_bin = max b with #{bin >= b} >= TOPK_N ----
  // block 0 only; S(0) = N_ANCH >= TOPK_N so the crossing exists.
  if (bid == 0) {
    const int CH = NBINS / NTHR;     // 16 reversed bins per thread
    int h16[CH];
    int sum = 0;
#pragma unroll
    for (int rr = 0; rr < CH; ++rr) {
      h16[rr] = ws->hist[NBINS - 1 - (tid * CH + rr)];
      sum += h16[rr];
    }
    part[tid] = sum;
    __syncthreads();
    for (int off = 1; off < NTHR; off <<= 1) {
      int v = (tid >= off) ? part[tid - off] : 0;
      __syncthreads();
      part[tid] += v;
      __syncthreads();
    }
    int cum = part[tid] - sum;       // count in bins above this thread's chunk
#pragma unroll
    for (int rr = 0; rr < CH; ++rr) {
      int b = NBINS - 1 - (tid * CH + rr);
      int h = h16[rr];
      int prev = cum;
      cum += h;
      if (prev < TOPK_N && cum >= TOPK_N) ws->t_bin = b;  // unique crossing thread
    }
  }
  grid.sync();

  // ---------------- phase 3: compact (wave-aggregated atomic) ------------
  {
    bool want = false;
    if (gtid < N_ANCH) want = (ws->binv[gtid] >= ws->t_bin);
    u64 mask = __ballot(want);
    if (mask) {
      int lane = tid & 63;
      int lead = __ffsll(mask) - 1;
      int pre  = __popcll(mask & ((1ull << lane) - 1ull));
      int base = 0;
      if (lane == lead) base = atomicAdd(&ws->m_count, __popcll(mask));
      base = __shfl(base, lead);
      if (want) {
        int idx = base + pre;
        ws->subset[idx] = gtid;
        ws->ssc[idx] = ws->sc[gtid];
        ws->rank[idx] = 0;
      }
    }
  }
  grid.sync();

  // ---------------- phase 4: exact rank within subset --------------------
  // rank[i] = #{ j : sc_j > sc_i or (sc_j==sc_i && aj<ai) }
  {
    int m = ws->m_count;
    int itc = (m + NTHR - 1) / NTHR;
    int ntask = itc * JS;
    int jlen = (m + JS - 1) / JS;
    for (int task = bid; task < ntask; task += NBLK) {
      int it = task / JS, js = task % JS;
      int i = it * NTHR + tid;
      bool active = (i < m);
      int ai = active ? ws->subset[i] : 0;
      double si = active ? ws->ssc[i] : -2.0;
      int j0 = js * jlen;
      int jend = min(j0 + jlen, m);
      int cnt = 0;
      for (int jc0 = j0; jc0 < jend; jc0 += NTHR) {
        int n = min(NTHR, jend - jc0);
        __syncthreads();
        if (tid < n) { ajA[tid] = ws->subset[jc0 + tid]; sjD[tid] = ws->ssc[jc0 + tid]; }
        __syncthreads();
        if (active) {
          for (int t = 0; t < n; ++t) {
            double s = sjD[t];
            cnt += (int)((s > si) | ((s == si) & (ajA[t] < ai)));
          }
        }
      }
      if (active && cnt) atomicAdd(&ws->rank[i], cnt);
    }
  }
  grid.sync();

  // ---------------- phase 5: scatter into rank-ordered top-K -------------
  {
    int m = ws->m_count;
    if (gtid < m) {
      int r = ws->rank[gtid];
      if (r < TOPK_N) {
        int a = ws->subset[gtid];
        double b0 = ws->box[a][0], b1 = ws->box[a][1];
        double b2 = ws->box[a][2], b3 = ws->box[a][3];
        double s  = ws->ssc[gtid];
        int    c  = ws->cls[a];
        ws->tbox[r][0] = b0; ws->tbox[r][1] = b1;
        ws->tbox[r][2] = b2; ws->tbox[r][3] = b3;
        ws->tarea[r] = (b2 - b0) * (b3 - b1);
        ws->tsc[r] = s;
        ws->tcls[r] = c;
        out[r * 4 + 0] = (float)b0;
        out[r * 4 + 1] = (float)b1;
        out[r * 4 + 2] = (float)b2;
        out[r * 4 + 3] = (float)b3;
        out[4 * TOPK_N + r] = (float)s;
        out[5 * TOPK_N + r] = (float)c;
      }
    }
  }
  grid.sync();

  // ---------------- phase 6: suppression bit-matrix ----------------------
  // tile = (bi: 256 i-rows) x (wp: 2 words = 128 j). 512 tiles, 2 per block.
  {
    for (int task = bid; task < 512; task += NBLK) {
      int biT = task >> 5, wp = task & 31;
      int i0 = biT * 256;
      int jb0 = wp * 128;
      int il = tid & 255;
      int wq = tid >> 8;              // 0 or 1
      int w = wp * 2 + wq;
      int jbase = w * 64;
      int i = i0 + il;
      if (jb0 >= i0 + 256) {          // tile-uniform: whole tile is j > i
        ws->supT[(size_t)i * 64 + w] = 0ull;
      } else {
        __syncthreads();
        if (tid < 128) {
          int j = jb0 + tid;
          jbD[tid][0] = ws->tbox[j][0];
          jbD[tid][1] = ws->tbox[j][1];
          jbD[tid][2] = ws->tbox[j][2];
          jbD[tid][3] = ws->tbox[j][3];
          jbD[tid][4] = ws->tarea[j];
          jcA[tid] = ws->tcls[j];
        }
        __syncthreads();
        double x1 = ws->tbox[i][0], y1 = ws->tbox[i][1];
        double x2 = ws->tbox[i][2], y2 = ws->tbox[i][3];
        double ai = ws->tarea[i];
        int ci = ws->tcls[i];
        int tb = wq * 64;
        u64 bits = 0;
        for (int t = 0; t < 64; ++t) {
          double xx1 = fmax(x1, jbD[tb + t][0]);
          double yy1 = fmax(y1, jbD[tb + t][1]);
          double xx2 = fmin(x2, jbD[tb + t][2]);
          double yy2 = fmin(y2, jbD[tb + t][3]);
          double iw = fmax(1e-28, xx2 - xx1);
          double ih = fmax(1e-28, yy2 - yy1);
          double inter = iw * ih;
          double denom = ai + jbD[tb + t][4] - inter + 1e-14;
          bool sup = (jcA[tb + t] == ci) && (inter > NMS_T * denom) && ((jbase + t) < i);
          bits |= ((u64)sup) << t;
        }
        ws->supT[(size_t)i * 64 + w] = bits;
        if (bits) atomicOr(&ws->hasSup[i >> 6], 1ull << (i & 63));
      }
    }
  }
  grid.sync();

  // ---------------- phase 7: greedy NMS over contested candidates --------
  // block 0 only; wave 0 (tid<64) does the work, barriers are block-wide.
  if (bid == 0) {
    bool w0 = (tid < 64);
    int lane = tid;
    u64 validw = 0, hasw = 0, keepw = 0;
    if (w0) {
      const double4* tp = (const double4*)(ws->tsc + lane * 64);
      for (int q = 0; q < 16; ++q) {
        double4 v = tp[q];
        validw |= ((u64)(v.x >= CONF_T)) << (q * 4 + 0);
        validw |= ((u64)(v.y >= CONF_T)) << (q * 4 + 1);
        validw |= ((u64)(v.z >= CONF_T)) << (q * 4 + 2);
        validw |= ((u64)(v.w >= CONF_T)) << (q * 4 + 3);
      }
      hasw = ws->hasSup[lane];
      keepw = validw & ~hasw;         // bulk-keep uncontested valid candidates
      hsArr[lane] = hasw;
    }
    __syncthreads();

    int K = 0;
    if (w0) {
      for (int l = 0; l < 64; ++l) {
        u64 wv = hsArr[l];
        while (wv) {
          int b = __builtin_ctzll(wv);
          wv &= wv - 1;
          if (lane == 0) lst[K] = l * 64 + b;
          ++K;
        }
      }
    }
    __syncthreads();

    if (w0) {
      const u64* ST = ws->supT;
      int IA[16], IB[16];
      u64 A[16], B[16];

#pragma unroll
      for (int r = 0; r < 16; ++r) IA[r] = (r < K) ? lst[r] : 0;
#pragma unroll
      for (int r = 0; r < 16; ++r) A[r] = (r < K) ? ST[(size_t)IA[r] * 64 + lane] : 0ull;

      for (int base = 0; base < K; base += 32) {
#pragma unroll
        for (int r = 0; r < 16; ++r) IB[r] = (base + 16 + r < K) ? lst[base + 16 + r] : 0;
#pragma unroll
        for (int r = 0; r < 16; ++r) B[r] = (base + 16 + r < K) ? ST[(size_t)IB[r] * 64 + lane] : 0ull;
#pragma unroll
        for (int r = 0; r < 16; ++r) {
          if (base + r < K) {
            int i = IA[r];
            u64 bal = __ballot((keepw & A[r]) != 0ull);
            if (lane == (i >> 6) && bal == 0ull && ((validw >> (i & 63)) & 1ull))
              keepw |= 1ull << (i & 63);
          }
        }
#pragma unroll
        for (int r = 0; r < 16; ++r) IA[r] = (base + 32 + r < K) ? lst[base + 32 + r] : 0;
#pragma unroll
        for (int r = 0; r < 16; ++r) A[r] = (base + 32 + r < K) ? ST[(size_t)IA[r] * 64 + lane] : 0ull;
#pragma unroll
        for (int r = 0; r < 16; ++r) {
          if (base + 16 + r < K) {
            int i = IB[r];
            u64 bal = __ballot((keepw & B[r]) != 0ull);
            if (lane == (i >> 6) && bal == 0ull && ((validw >> (i & 63)) & 1ull))
              keepw |= 1ull << (i & 63);
          }
        }
      }

      for (int b = 0; b < 64; ++b)
        out[6 * TOPK_N + lane * 64 + b] = (float)((keepw >> b) & 1ull);
    }
  }
}

extern "C" void kernel_launch(void* const* d_in, const int* in_sizes, int n_in,
                              void* d_out, int out_size, void* d_ws, size_t ws_size,
                              hipStream_t stream) {
  const float* ps   = (const float*)d_in[0];
  const float* pm   = (const float*)d_in[1];
  const float* pl   = (const float*)d_in[2];
  const float* anch = (const float*)d_in[3];
  float* out = (float*)d_out;
  WS* ws = (WS*)d_ws;

  void* args[] = { (void*)&ps, (void*)&pm, (void*)&pl, (void*)&anch, (void*)&ws, (void*)&out };
  hipLaunchCooperativeKernel((void*)k_all, dim3(NBLK), dim3(NTHR), args, 0, stream);
}

// Round 2
// 225.635 us; speedup vs baseline: 1.3732x; 1.3732x over previous
//
#include <hip/hip_runtime.h>
#include <cstdint>
#include <cstddef>

#define N_ANCH 25200
#define NB0 19200
#define NB1 24000
#define TOPK_N 4096
#define CONF_T 0.001
#define NMS_T 0.6
#define IMGS 640.0
#define NBINS 8192       // fp32 bits >> 17 (exponent + 6 mantissa bits)

#define K1_B 512
#define K1_G 197         // ceil(25200*4 / 512)
#define K2_B 1024
#define K2_IBMAX 25      // ceil(25200 / 1024)
#define K2_JS 16
#define K3_B 256

typedef unsigned long long u64;
typedef unsigned int u32;

struct WS {
  alignas(64) double sc[N_ANCH];       // masked score (sc or -1.0), fp64
  alignas(64) double box[N_ANCH][4];   // clipped normalized boxes, fp64
  alignas(64) int    cls[N_ANCH];
  alignas(64) int    binv[N_ANCH];     // score bin per anchor
  alignas(64) int    rank[N_ANCH];     // rank within subset
  alignas(64) int    subset[N_ANCH];   // anchor ids with bin >= t_bin
  alignas(64) u64    skey[N_ANCH];     // (sortable fp32 bits << 32) | (~anchor id)
  alignas(64) u64    hasSup[64];
  int    m_count;
  alignas(64) double tbox[TOPK_N][4];
  alignas(64) double tarea[TOPK_N];
  alignas(64) double tsc[TOPK_N];
  alignas(64) int    tcls[TOPK_N];
  alignas(64) u64    supT[TOPK_N * 64]; // supT[i*64+w] bit b: j=w*64+b suppresses i
};

// phase-completion counters: device globals (NOT in poisoned workspace),
// zero-initialized at module load, reset by each kernel's own last block.
__device__ u32 d_c1 = 0;
__device__ u32 d_c2 = 0;
__device__ u32 d_c3 = 0;

__device__ __forceinline__ double dsigmoid(double x) { return 1.0 / (1.0 + exp(-x)); }

__device__ __forceinline__ int score_bin(double sc) {
  if (sc < 0.0) return 0;                          // masked
  return (int)(__float_as_uint((float)sc) >> 17);  // monotone for positive floats, < 8192
}

// sortable total order on fp32 bits (handles negatives, i.e. the -1.0 mask)
__device__ __forceinline__ u32 sortable32(float f) {
  u32 fb = __float_as_uint(f);
  return fb ^ ((fb & 0x80000000u) ? 0xFFFFFFFFu : 0x80000000u);
}

// all blocks call; returns true in exactly the last-finishing block.
// Release: each arriver publishes its stores (threadfence + acq_rel add).
// Acquire: last block fences before reading others' data.
__device__ __forceinline__ bool last_block(u32* ctr, u32 total) {
  __shared__ int isLast;
  __syncthreads();
  if (threadIdx.x == 0) {
    __threadfence();  // agent-scope release of this block's stores
    u32 old = __hip_atomic_fetch_add(ctr, 1u, __ATOMIC_ACQ_REL, __HIP_MEMORY_SCOPE_AGENT);
    isLast = (old == total - 1u);
    if (isLast) __hip_atomic_store(ctr, 0u, __ATOMIC_RELAXED, __HIP_MEMORY_SCOPE_AGENT);
  }
  __syncthreads();
  if (isLast) { __threadfence(); return true; }  // acquire for all threads
  return false;
}

// ---------------- k1: decode (all blocks) + last-block {select, compact} ---
__global__ void __launch_bounds__(K1_B)
k1_decode(const float* __restrict__ ps, const float* __restrict__ pm,
          const float* __restrict__ pl, const float* __restrict__ anch,
          WS* __restrict__ ws) {
  __shared__ int hist[NBINS];   // 32 KB (epilogue only)
  __shared__ int part[K1_B];
  __shared__ int tbin_s;
  __shared__ int mcnt;

  const int tid  = threadIdx.x;
  const int gtid = blockIdx.x * K1_B + tid;
  {
    int a = gtid >> 2;
    int r = gtid & 3;
    if (a < N_ANCH) {
      const float* p; int W, base, lvl; double stride;
      if (a < NB0)      { p = ps; W = 80; base = 0;   lvl = 0; stride = 8.0; }
      else if (a < NB1) { p = pm; W = 40; base = NB0; lvl = 1; stride = 16.0; }
      else              { p = pl; W = 20; base = NB1; lvl = 2; stride = 32.0; }
      int e = a - base;
      int pos = e / 3;
      int k = e - 3 * pos;
      int HW = W * W;

      // class max/argmax + softmax denom, 20 classes per lane (teams of 4, wave-aligned)
      const float* pc = p + (size_t)(3 + k * 80) * HW + pos;
      double m = -1e300, ssum = 0.0; int am = 0;
      for (int t = 0; t < 20; ++t) {
        int c = r + 4 * t;
        double v = (double)pc[(size_t)c * HW];
        ssum += exp(v);
        if (v > m) { m = v; am = c; }
      }
      for (int off = 1; off <= 2; off <<= 1) {
        double om = __shfl_xor(m, off);
        int oam   = __shfl_xor(am, off);
        double os = __shfl_xor(ssum, off);
        ssum += os;
        if (om > m || (om == m && oam < am)) { m = om; am = oam; }
      }

      if (r == 0) {
        double sobj = dsigmoid((double)p[(size_t)k * HW + pos]);
        double sc = sobj * (exp(m) / ssum);

        int x = pos % W, y = pos / W;
        const float* pr = p + (size_t)(243 + k * 4) * HW + pos;
        double tx = (double)pr[0];
        double ty = (double)pr[(size_t)HW];
        double tw = (double)pr[(size_t)2 * HW];
        double th = (double)pr[(size_t)3 * HW];
        double cx = (dsigmoid(tx) + (double)x) * stride;
        double cy = (dsigmoid(ty) + (double)y) * stride;
        double aw = (double)anch[lvl * 6 + k * 2 + 0];
        double ah = (double)anch[lvl * 6 + k * 2 + 1];
        double bw = exp(tw) * aw;
        double bh = exp(th) * ah;
        double x1 = fmin(fmax((cx - 0.5 * bw) / IMGS, 0.0), 1.0);
        double y1 = fmin(fmax((cy - 0.5 * bh) / IMGS, 0.0), 1.0);
        double x2 = fmin(fmax((cx + 0.5 * bw) / IMGS, 0.0), 1.0);
        double y2 = fmin(fmax((cy + 0.5 * bh) / IMGS, 0.0), 1.0);

        ws->box[a][0] = x1; ws->box[a][1] = y1;
        ws->box[a][2] = x2; ws->box[a][3] = y2;
        ws->cls[a] = am;
        double scm = (sc >= CONF_T) ? sc : -1.0;
        ws->sc[a] = scm;
        ws->binv[a] = score_bin(scm);
      }
    }
  }

  if (!last_block(&d_c1, K1_G)) return;

  // ---- epilogue (one block, 512 thr): select t_bin, zero hasSup, compact ----
  for (int i = tid; i < NBINS; i += K1_B) hist[i] = 0;
  __syncthreads();
  for (int i = tid; i < N_ANCH; i += K1_B) atomicAdd(&hist[ws->binv[i]], 1);
  __syncthreads();
  const int CH = NBINS / K1_B;   // 16 reversed bins per thread
  int h16[CH];
  int sum = 0;
#pragma unroll
  for (int rr = 0; rr < CH; ++rr) {
    h16[rr] = hist[NBINS - 1 - (tid * CH + rr)];
    sum += h16[rr];
  }
  part[tid] = sum;
  __syncthreads();
  for (int off = 1; off < K1_B; off <<= 1) {
    int v = (tid >= off) ? part[tid - off] : 0;
    __syncthreads();
    part[tid] += v;
    __syncthreads();
  }
  int cum = part[tid] - sum;
#pragma unroll
  for (int rr = 0; rr < CH; ++rr) {
    int b = NBINS - 1 - (tid * CH + rr);
    int prev = cum;
    cum += h16[rr];
    if (prev < TOPK_N && cum >= TOPK_N) tbin_s = b;   // unique crossing thread
  }
  if (tid < 64) ws->hasSup[tid] = 0ull;
  if (tid == 0) mcnt = 0;
  __syncthreads();
  int tb = tbin_s;

  for (int i0 = 0; i0 < N_ANCH; i0 += K1_B) {
    int i = i0 + tid;
    bool want = (i < N_ANCH) && (ws->binv[i] >= tb);
    u64 mask = __ballot(want);
    if (mask) {
      int lane = tid & 63;
      int lead = __ffsll((long long)mask) - 1;
      int pre  = __popcll(mask & ((1ull << lane) - 1ull));
      int base = 0;
      if (lane == lead) base = atomicAdd(&mcnt, (int)__popcll(mask));
      base = __shfl(base, lead);
      if (want) {
        int idx = base + pre;
        ws->subset[idx] = i;
        u32 k32 = sortable32((float)ws->sc[i]);
        ws->skey[idx] = ((u64)k32 << 32) | (u64)(0xFFFFFFFFu - (u32)i);
        ws->rank[idx] = 0;
      }
    }
  }
  __syncthreads();
  if (tid == 0) ws->m_count = mcnt;
}

// ---------------- k2: rank (active blocks) + last-block {scatter} ----------
__global__ void __launch_bounds__(K2_B)
k2_rank(WS* __restrict__ ws, float* __restrict__ out) {
  __shared__ u64 sk[K2_B];
  const int tid = threadIdx.x;
  int m = ws->m_count;
  int nIB = (m + K2_B - 1) / K2_B;
  if ((int)blockIdx.x >= nIB) return;   // inactive: excluded from completion count

  int i = blockIdx.x * K2_B + tid;
  bool active = (i < m);
  u64 ki = active ? ws->skey[i] : 0ull;
  int jlen = (m + K2_JS - 1) / K2_JS;
  int j0 = blockIdx.y * jlen;
  int jend = min(j0 + jlen, m);
  int cnt = 0;
  for (int jc = j0; jc < jend; jc += K2_B) {
    int n = min(K2_B, jend - jc);
    __syncthreads();
    if (tid < n) sk[tid] = ws->skey[jc + tid];
    __syncthreads();
    if (active) {
      for (int t = 0; t < n; ++t) cnt += (int)(sk[t] > ki);
    }
  }
  if (active && cnt) atomicAdd(&ws->rank[i], cnt);

  if (!last_block(&d_c2, (u32)(nIB * K2_JS))) return;

  // ---- epilogue: scatter into rank-ordered top-K ----
  for (int idx = tid; idx < m; idx += K2_B) {
    int r = ws->rank[idx];
    if (r < TOPK_N) {
      int a = ws->subset[idx];
      double b0 = ws->box[a][0], b1 = ws->box[a][1];
      double b2 = ws->box[a][2], b3 = ws->box[a][3];
      double s  = ws->sc[a];
      int    c  = ws->cls[a];
      ws->tbox[r][0] = b0; ws->tbox[r][1] = b1;
      ws->tbox[r][2] = b2; ws->tbox[r][3] = b3;
      ws->tarea[r] = (b2 - b0) * (b3 - b1);
      ws->tsc[r] = s;
      ws->tcls[r] = c;
      out[r * 4 + 0] = (float)b0;
      out[r * 4 + 1] = (float)b1;
      out[r * 4 + 2] = (float)b2;
      out[r * 4 + 3] = (float)b3;
      out[4 * TOPK_N + r] = (float)s;
      out[5 * TOPK_N + r] = (float)c;
    }
  }
}

// ---------------- k3: iou bit-matrix (all blocks) + last-block {nms} -------
__global__ void __launch_bounds__(K3_B)
k3_iou(WS* __restrict__ ws, float* __restrict__ out) {
  __shared__ double jb[64][5];
  __shared__ int    jc[64];
  __shared__ u64    hsArr[64];
  __shared__ int    lst[TOPK_N];

  const int tid = threadIdx.x;
  const int i0 = blockIdx.x * K3_B;
  const int i = i0 + tid;

  double x1 = ws->tbox[i][0], y1 = ws->tbox[i][1];
  double x2 = ws->tbox[i][2], y2 = ws->tbox[i][3];
  double ai = ws->tarea[i];
  int ci = ws->tcls[i];

  for (int q = 0; q < 4; ++q) {
    int w = blockIdx.y * 4 + q;
    int jbase = w * 64;
    if (jbase >= i0 + K3_B) {            // block-uniform: whole word is j > i
      ws->supT[(size_t)i * 64 + w] = 0ull;
      continue;
    }
    __syncthreads();
    if (tid < 64) {
      int j = jbase + tid;
      jb[tid][0] = ws->tbox[j][0];
      jb[tid][1] = ws->tbox[j][1];
      jb[tid][2] = ws->tbox[j][2];
      jb[tid][3] = ws->tbox[j][3];
      jb[tid][4] = ws->tarea[j];
      jc[tid] = ws->tcls[j];
    }
    __syncthreads();
    u64 bits = 0;
    for (int t = 0; t < 64; ++t) {
      double xx1 = fmax(x1, jb[t][0]);
      double yy1 = fmax(y1, jb[t][1]);
      double xx2 = fmin(x2, jb[t][2]);
      double yy2 = fmin(y2, jb[t][3]);
      double iw = fmax(1e-28, xx2 - xx1);
      double ih = fmax(1e-28, yy2 - yy1);
      double inter = iw * ih;
      double denom = ai + jb[t][4] - inter + 1e-14;
      bool sup = (jc[t] == ci) && (inter > NMS_T * denom) && ((jbase + t) < i);
      bits |= ((u64)sup) << t;
    }
    ws->supT[(size_t)i * 64 + w] = bits;
    if (bits) atomicOr(&ws->hasSup[i >> 6], 1ull << (i & 63));
  }

  if (!last_block(&d_c3, 16u * 16u)) return;

  // ---- epilogue: greedy NMS over contested candidates (wave 0 works) ----
  {
    bool w0 = (tid < 64);
    int lane = tid;
    u64 validw = 0, hasw = 0, keepw = 0;
    if (w0) {
      const double4* tp = (const double4*)(ws->tsc + lane * 64);
      for (int q = 0; q < 16; ++q) {
        double4 v = tp[q];
        validw |= ((u64)(v.x >= CONF_T)) << (q * 4 + 0);
        validw |= ((u64)(v.y >= CONF_T)) << (q * 4 + 1);
        validw |= ((u64)(v.z >= CONF_T)) << (q * 4 + 2);
        validw |= ((u64)(v.w >= CONF_T)) << (q * 4 + 3);
      }
      hasw = ws->hasSup[lane];
      keepw = validw & ~hasw;       // bulk-keep uncontested valid candidates
      hsArr[lane] = hasw;
    }
    __syncthreads();

    int K = 0;
    if (w0) {
      for (int l = 0; l < 64; ++l) {
        u64 wv = hsArr[l];
        while (wv) {
          int b = __builtin_ctzll(wv);
          wv &= wv - 1;
          if (lane == 0) lst[K] = l * 64 + b;
          ++K;
        }
      }
    }
    __syncthreads();

    if (w0) {
      const u64* ST = ws->supT;
      int IA[16], IB[16];
      u64 A[16], B[16];

#pragma unroll
      for (int r = 0; r < 16; ++r) IA[r] = (r < K) ? lst[r] : 0;
#pragma unroll
      for (int r = 0; r < 16; ++r) A[r] = (r < K) ? ST[(size_t)IA[r] * 64 + lane] : 0ull;

      for (int base = 0; base < K; base += 32) {
#pragma unroll
        for (int r = 0; r < 16; ++r) IB[r] = (base + 16 + r < K) ? lst[base + 16 + r] : 0;
#pragma unroll
        for (int r = 0; r < 16; ++r) B[r] = (base + 16 + r < K) ? ST[(size_t)IB[r] * 64 + lane] : 0ull;
#pragma unroll
        for (int r = 0; r < 16; ++r) {
          if (base + r < K) {
            int i2 = IA[r];
            u64 bal = __ballot((keepw & A[r]) != 0ull);
            if (lane == (i2 >> 6) && bal == 0ull && ((validw >> (i2 & 63)) & 1ull))
              keepw |= 1ull << (i2 & 63);
          }
        }
#pragma unroll
        for (int r = 0; r < 16; ++r) IA[r] = (base + 32 + r < K) ? lst[base + 32 + r] : 0;
#pragma unroll
        for (int r = 0; r < 16; ++r) A[r] = (base + 32 + r < K) ? ST[(size_t)IA[r] * 64 + lane] : 0ull;
#pragma unroll
        for (int r = 0; r < 16; ++r) {
          if (base + 16 + r < K) {
            int i2 = IB[r];
            u64 bal = __ballot((keepw & B[r]) != 0ull);
            if (lane == (i2 >> 6) && bal == 0ull && ((validw >> (i2 & 63)) & 1ull))
              keepw |= 1ull << (i2 & 63);
          }
        }
      }

      for (int b = 0; b < 64; ++b)
        out[6 * TOPK_N + lane * 64 + b] = (float)((keepw >> b) & 1ull);
    }
  }
}

extern "C" void kernel_launch(void* const* d_in, const int* in_sizes, int n_in,
                              void* d_out, int out_size, void* d_ws, size_t ws_size,
                              hipStream_t stream) {
  const float* ps   = (const float*)d_in[0];
  const float* pm   = (const float*)d_in[1];
  const float* pl   = (const float*)d_in[2];
  const float* anch = (const float*)d_in[3];
  float* out = (float*)d_out;
  WS* ws = (WS*)d_ws;

  k1_decode<<<dim3(K1_G), dim3(K1_B), 0, stream>>>(ps, pm, pl, anch, ws);
  k2_rank  <<<dim3(K2_IBMAX, K2_JS), dim3(K2_B), 0, stream>>>(ws, out);
  k3_iou   <<<dim3(TOPK_N / K3_B, 16), dim3(K3_B), 0, stream>>>(ws, out);
}

// Round 3
// 191.184 us; speedup vs baseline: 1.6207x; 1.1802x over previous
//
#include <hip/hip_runtime.h>
#include <cstdint>
#include <cstddef>

#define N_ANCH 25200
#define NB0 19200
#define NB1 24000
#define TOPK_N 4096
#define CONF_T 0.001
#define NMS_T 0.6
#define IMGS 640.0
#define NBINS 8192       // fp32 bits >> 17 (exponent + 6 mantissa bits)

#define K1_B 512
#define K1_G 197         // ceil(25200*4 / 512)
#define K2_B 1024
#define K2_IBMAX 25      // ceil(25200 / 1024)
#define K2_JS 16
#define NCLS 80

typedef unsigned long long u64;
typedef unsigned int u32;

struct WS {
  alignas(64) double sc[N_ANCH];       // masked score (sc or -1.0), fp64
  alignas(64) double box[N_ANCH][4];   // clipped normalized boxes, fp64
  alignas(64) int    cls[N_ANCH];
  alignas(64) int    binv[N_ANCH];     // score bin per anchor
  alignas(64) int    rank[N_ANCH];     // rank within subset
  alignas(64) int    subset[N_ANCH];   // anchor ids with bin >= t_bin
  alignas(64) u64    skey[N_ANCH];     // (sortable fp32 bits << 32) | (~anchor id)
  int    m_count;
  alignas(64) double tbox[TOPK_N][4];
  alignas(64) double tarea[TOPK_N];
  alignas(64) double tsc[TOPK_N];
  alignas(64) int    tcls[TOPK_N];
};

// phase-completion counters: device globals, zero-init at load,
// reset by each kernel's own last block (graph-replay safe).
__device__ u32 d_c1 = 0;
__device__ u32 d_c2 = 0;

__device__ __forceinline__ double dsigmoid(double x) { return 1.0 / (1.0 + exp(-x)); }

__device__ __forceinline__ int score_bin(double sc) {
  if (sc < 0.0) return 0;                          // masked
  return (int)(__float_as_uint((float)sc) >> 17);  // monotone for positive floats, < 8192
}

// sortable total order on fp32 bits (handles negatives, i.e. the -1.0 mask)
__device__ __forceinline__ u32 sortable32(float f) {
  u32 fb = __float_as_uint(f);
  return fb ^ ((fb & 0x80000000u) ? 0xFFFFFFFFu : 0x80000000u);
}

// Fence-cheap last-block detection:
//  - arrivers: every thread drains its own stores (vmcnt 0; agent-coherent
//    sc1 stores are then AT the coherence point), barrier, one RELAXED
//    agent RMW. No wbl2/inv in arriving blocks.
//  - last block only: one __threadfence() (L2 wb/inv on ITS XCD) before
//    reading other blocks' data.
__device__ __forceinline__ bool last_block(u32* ctr, u32 total) {
  __shared__ int isLast;
  asm volatile("s_waitcnt vmcnt(0)" ::: "memory");
  __syncthreads();
  if (threadIdx.x == 0) {
    u32 old = __hip_atomic_fetch_add(ctr, 1u, __ATOMIC_RELAXED, __HIP_MEMORY_SCOPE_AGENT);
    int last = (old == total - 1u) ? 1 : 0;
    if (last) {
      __hip_atomic_store(ctr, 0u, __ATOMIC_RELAXED, __HIP_MEMORY_SCOPE_AGENT);
      __threadfence();   // acquire: invalidate this CU/XCD caches once
    }
    isLast = last;
  }
  __syncthreads();
  return isLast != 0;
}

// ---------------- k1: decode (all blocks) + last-block {select, compact} ---
__global__ void __launch_bounds__(K1_B)
k1_decode(const float* __restrict__ ps, const float* __restrict__ pm,
          const float* __restrict__ pl, const float* __restrict__ anch,
          WS* __restrict__ ws) {
  __shared__ int hist[NBINS];   // 32 KB (epilogue only)
  __shared__ int part[K1_B];
  __shared__ int tbin_s;
  __shared__ int mcnt;

  const int tid  = threadIdx.x;
  const int gtid = blockIdx.x * K1_B + tid;
  {
    int a = gtid >> 2;
    int r = gtid & 3;
    if (a < N_ANCH) {
      const float* p; int W, base, lvl; double stride;
      if (a < NB0)      { p = ps; W = 80; base = 0;   lvl = 0; stride = 8.0; }
      else if (a < NB1) { p = pm; W = 40; base = NB0; lvl = 1; stride = 16.0; }
      else              { p = pl; W = 20; base = NB1; lvl = 2; stride = 32.0; }
      int e = a - base;
      int pos = e / 3;
      int k = e - 3 * pos;
      int HW = W * W;

      // class max/argmax + softmax denom, 20 classes per lane (teams of 4, wave-aligned)
      const float* pc = p + (size_t)(3 + k * 80) * HW + pos;
      double m = -1e300, ssum = 0.0; int am = 0;
      for (int t = 0; t < 20; ++t) {
        int c = r + 4 * t;
        double v = (double)pc[(size_t)c * HW];
        ssum += exp(v);
        if (v > m) { m = v; am = c; }
      }
      for (int off = 1; off <= 2; off <<= 1) {
        double om = __shfl_xor(m, off);
        int oam   = __shfl_xor(am, off);
        double os = __shfl_xor(ssum, off);
        ssum += os;
        if (om > m || (om == m && oam < am)) { m = om; am = oam; }
      }

      if (r == 0) {
        double sobj = dsigmoid((double)p[(size_t)k * HW + pos]);
        double sc = sobj * (exp(m) / ssum);

        int x = pos % W, y = pos / W;
        const float* pr = p + (size_t)(243 + k * 4) * HW + pos;
        double tx = (double)pr[0];
        double ty = (double)pr[(size_t)HW];
        double tw = (double)pr[(size_t)2 * HW];
        double th = (double)pr[(size_t)3 * HW];
        double cx = (dsigmoid(tx) + (double)x) * stride;
        double cy = (dsigmoid(ty) + (double)y) * stride;
        double aw = (double)anch[lvl * 6 + k * 2 + 0];
        double ah = (double)anch[lvl * 6 + k * 2 + 1];
        double bw = exp(tw) * aw;
        double bh = exp(th) * ah;
        double x1 = fmin(fmax((cx - 0.5 * bw) / IMGS, 0.0), 1.0);
        double y1 = fmin(fmax((cy - 0.5 * bh) / IMGS, 0.0), 1.0);
        double x2 = fmin(fmax((cx + 0.5 * bw) / IMGS, 0.0), 1.0);
        double y2 = fmin(fmax((cy + 0.5 * bh) / IMGS, 0.0), 1.0);

        ws->box[a][0] = x1; ws->box[a][1] = y1;      // plain (read after k1 ends)
        ws->box[a][2] = x2; ws->box[a][3] = y2;
        ws->cls[a] = am;
        double scm = (sc >= CONF_T) ? sc : -1.0;
        // binv + sc are read by THIS kernel's last-block epilogue from other
        // blocks -> agent-coherent (write-through) stores, no fence needed.
        __hip_atomic_store(&ws->sc[a], scm, __ATOMIC_RELAXED, __HIP_MEMORY_SCOPE_AGENT);
        __hip_atomic_store(&ws->binv[a], score_bin(scm), __ATOMIC_RELAXED, __HIP_MEMORY_SCOPE_AGENT);
      }
    }
  }

  if (!last_block(&d_c1, K1_G)) return;

  // ---- epilogue (one block, 512 thr): select t_bin, compact ----
  for (int i = tid; i < NBINS; i += K1_B) hist[i] = 0;
  __syncthreads();
  for (int i = tid; i < N_ANCH; i += K1_B) atomicAdd(&hist[ws->binv[i]], 1);
  __syncthreads();
  const int CH = NBINS / K1_B;   // 16 reversed bins per thread
  int h16[CH];
  int sum = 0;
#pragma unroll
  for (int rr = 0; rr < CH; ++rr) {
    h16[rr] = hist[NBINS - 1 - (tid * CH + rr)];
    sum += h16[rr];
  }
  part[tid] = sum;
  __syncthreads();
  for (int off = 1; off < K1_B; off <<= 1) {
    int v = (tid >= off) ? part[tid - off] : 0;
    __syncthreads();
    part[tid] += v;
    __syncthreads();
  }
  int cum = part[tid] - sum;
#pragma unroll
  for (int rr = 0; rr < CH; ++rr) {
    int b = NBINS - 1 - (tid * CH + rr);
    int prev = cum;
    cum += h16[rr];
    if (prev < TOPK_N && cum >= TOPK_N) tbin_s = b;   // unique crossing thread
  }
  if (tid == 0) mcnt = 0;
  __syncthreads();
  int tb = tbin_s;

  for (int i0 = 0; i0 < N_ANCH; i0 += K1_B) {
    int i = i0 + tid;
    bool want = (i < N_ANCH) && (ws->binv[i] >= tb);
    u64 mask = __ballot(want);
    if (mask) {
      int lane = tid & 63;
      int lead = __ffsll((long long)mask) - 1;
      int pre  = __popcll(mask & ((1ull << lane) - 1ull));
      int base = 0;
      if (lane == lead) base = atomicAdd(&mcnt, (int)__popcll(mask));
      base = __shfl(base, lead);
      if (want) {
        int idx = base + pre;
        ws->subset[idx] = i;
        u32 k32 = sortable32((float)ws->sc[i]);
        ws->skey[idx] = ((u64)k32 << 32) | (u64)(0xFFFFFFFFu - (u32)i);
        ws->rank[idx] = 0;
      }
    }
  }
  __syncthreads();
  if (tid == 0) ws->m_count = mcnt;
}

// ---------------- k2: rank (active blocks) + last-block {scatter} ----------
__global__ void __launch_bounds__(K2_B)
k2_rank(WS* __restrict__ ws, float* __restrict__ out) {
  __shared__ u64 sk[K2_B];
  const int tid = threadIdx.x;
  int m = ws->m_count;
  int nIB = (m + K2_B - 1) / K2_B;
  if ((int)blockIdx.x >= nIB) return;   // inactive: excluded from completion count

  int i = blockIdx.x * K2_B + tid;
  bool active = (i < m);
  u64 ki = active ? ws->skey[i] : 0ull;
  int jlen = (m + K2_JS - 1) / K2_JS;
  int j0 = blockIdx.y * jlen;
  int jend = min(j0 + jlen, m);
  int cnt = 0;
  for (int jc = j0; jc < jend; jc += K2_B) {
    int n = min(K2_B, jend - jc);
    __syncthreads();
    if (tid < n) sk[tid] = ws->skey[jc + tid];
    __syncthreads();
    if (active) {
      for (int t = 0; t < n; ++t) cnt += (int)(sk[t] > ki);
    }
  }
  // rank accumulates via device-scope RMWs (coherence-point) -> no extra release
  if (active && cnt) atomicAdd(&ws->rank[i], cnt);

  if (!last_block(&d_c2, (u32)(nIB * K2_JS))) return;

  // ---- epilogue: scatter into rank-ordered top-K ----
  for (int idx = tid; idx < m; idx += K2_B) {
    int r = ws->rank[idx];
    if (r < TOPK_N) {
      int a = ws->subset[idx];
      double b0 = ws->box[a][0], b1 = ws->box[a][1];
      double b2 = ws->box[a][2], b3 = ws->box[a][3];
      double s  = ws->sc[a];
      int    c  = ws->cls[a];
      ws->tbox[r][0] = b0; ws->tbox[r][1] = b1;
      ws->tbox[r][2] = b2; ws->tbox[r][3] = b3;
      ws->tarea[r] = (b2 - b0) * (b3 - b1);
      ws->tsc[r] = s;
      ws->tcls[r] = c;
      out[r * 4 + 0] = (float)b0;
      out[r * 4 + 1] = (float)b1;
      out[r * 4 + 2] = (float)b2;
      out[r * 4 + 3] = (float)b3;
      out[4 * TOPK_N + r] = (float)s;
      out[5 * TOPK_N + r] = (float)c;
    }
  }
}

// ---------------- k3: per-class greedy NMS (80 independent 1-wave blocks) --
// Classes never interact in the reference suppression (c[i]==c[j] required),
// and rank order restricted to one class preserves the global greedy order.
// Same fp64 predicate (inter > 0.6*denom) on the same tbox doubles
// => bit-identical keep flags vs the round-2 bit-matrix version.
__global__ void __launch_bounds__(64)
k3_nms(const WS* __restrict__ ws, float* __restrict__ out) {
  __shared__ int clsL[TOPK_N];           // staged tcls (16 KB)
  __shared__ int ridx[TOPK_N];           // this class's rows, rank order (16 KB)
  __shared__ int klist[TOPK_N];          // kept rows (overflow path) (16 KB)
  __shared__ unsigned char keepF[TOPK_N];

  const int lane = threadIdx.x;
  const int c = blockIdx.x;

  // stage tcls to LDS (wide loads)
  {
    const int4* src = (const int4*)ws->tcls;
    int4* dst = (int4*)clsL;
    for (int q = lane; q < TOPK_N / 4; q += 64) dst[q] = src[q];
  }
  __syncthreads();

  // stable compact: rows of class c in ascending rank order
  int n = 0;
  const u64 lt = (1ull << lane) - 1ull;
  for (int base = 0; base < TOPK_N; base += 64) {
    bool want = (clsL[base + lane] == c);
    u64 mk = __ballot(want);
    if (want) ridx[n + __popcll(mk & lt)] = base + lane;
    n += (int)__popcll(mk);
  }

  // greedy: lane j holds kept box j (j<64); overflow via klist + global reads
  double kx1 = 0, ky1 = 0, kx2 = 0, ky2 = 0, ka = 0;
  int kn = 0;
  // prefetch candidate 0
  double nx1 = 0, ny1 = 0, nx2 = 0, ny2 = 0, na = 0, ns = -2.0;
  if (n > 0) {
    int r = ridx[0];
    nx1 = ws->tbox[r][0]; ny1 = ws->tbox[r][1];
    nx2 = ws->tbox[r][2]; ny2 = ws->tbox[r][3];
    na = ws->tarea[r]; ns = ws->tsc[r];
  }
  for (int q = 0; q < n; ++q) {
    double cx1 = nx1, cy1 = ny1, cx2 = nx2, cy2 = ny2, ca = na, cs = ns;
    int rcur = ridx[q];
    if (q + 1 < n) {                       // prefetch next candidate (broadcast)
      int r2 = ridx[q + 1];
      nx1 = ws->tbox[r2][0]; ny1 = ws->tbox[r2][1];
      nx2 = ws->tbox[r2][2]; ny2 = ws->tbox[r2][3];
      na = ws->tarea[r2]; ns = ws->tsc[r2];
    }
    bool sup = false;
    if (lane < kn && lane < 64) {
      double xx1 = fmax(cx1, kx1), yy1 = fmax(cy1, ky1);
      double xx2 = fmin(cx2, kx2), yy2 = fmin(cy2, ky2);
      double iw = fmax(1e-28, xx2 - xx1);
      double ih = fmax(1e-28, yy2 - yy1);
      double inter = iw * ih;
      double denom = ca + ka - inter + 1e-14;
      sup = inter > NMS_T * denom;
    }
    for (int kb = 64; kb < kn; kb += 64) { // overflow (kept > 64): global reread
      if (kb + lane < kn) {
        int kr = klist[kb + lane];
        double ox1 = ws->tbox[kr][0], oy1 = ws->tbox[kr][1];
        double ox2 = ws->tbox[kr][2], oy2 = ws->tbox[kr][3];
        double oa = ws->tarea[kr];
        double xx1 = fmax(cx1, ox1), yy1 = fmax(cy1, oy1);
        double xx2 = fmin(cx2, ox2), yy2 = fmin(cy2, oy2);
        double iw = fmax(1e-28, xx2 - xx1);
        double ih = fmax(1e-28, yy2 - yy1);
        double inter = iw * ih;
        double denom = ca + oa - inter + 1e-14;
        sup = sup || (inter > NMS_T * denom);
      }
    }
    u64 anyb = __ballot(sup);
    bool valid = (cs >= CONF_T);
    bool kp = valid && (anyb == 0ull);
    if (kp) {
      if (kn < 64 && lane == kn) { kx1 = cx1; ky1 = cy1; kx2 = cx2; ky2 = cy2; ka = ca; }
      if (lane == 0) klist[kn] = rcur;
      ++kn;
    }
    if (lane == 0) keepF[q] = kp ? 1 : 0;
  }
  __syncthreads();
  for (int q = lane; q < n; q += 64)
    out[6 * TOPK_N + ridx[q]] = (float)keepF[q];
}

extern "C" void kernel_launch(void* const* d_in, const int* in_sizes, int n_in,
                              void* d_out, int out_size, void* d_ws, size_t ws_size,
                              hipStream_t stream) {
  const float* ps   = (const float*)d_in[0];
  const float* pm   = (const float*)d_in[1];
  const float* pl   = (const float*)d_in[2];
  const float* anch = (const float*)d_in[3];
  float* out = (float*)d_out;
  WS* ws = (WS*)d_ws;

  k1_decode<<<dim3(K1_G), dim3(K1_B), 0, stream>>>(ps, pm, pl, anch, ws);
  k2_rank  <<<dim3(K2_IBMAX, K2_JS), dim3(K2_B), 0, stream>>>(ws, out);
  k3_nms   <<<dim3(NCLS), dim3(64), 0, stream>>>(ws, out);
}